// Round 8
// baseline (303.452 us; speedup 1.0000x reference)
//
#include <hip/hip_runtime.h>
#include <stdint.h>

#define N_ROWS 4096
#define D_DIM  1024
#define N_CAND 8192
#define TEMP_INV 20.0f

#define BM 256
#define BN 256
#define BK 64
#define NT 16  // K-tiles

typedef __attribute__((ext_vector_type(4)))  int   i32x4;
typedef __attribute__((ext_vector_type(8)))  int   i32x8;
typedef __attribute__((ext_vector_type(16))) float f32x16;

using gvoid = __attribute__((address_space(1))) void;
using lvoid = __attribute__((address_space(3))) void;

#define BAR() __builtin_amdgcn_s_barrier()
#define SCHED0() __builtin_amdgcn_sched_barrier(0)

// ---------------------------------------------------------------------------
// Kernel 1: normalize rows, convert to fp8 e4m3 (natural column order, as
// required by the 32x32x64 f8f6f4 fragment layout: lane holds 32 contiguous
// k). cand = [P; N]. Also zeroes rowsum.
// ---------------------------------------------------------------------------
__global__ __launch_bounds__(256) void prep_kernel(
    const float* __restrict__ s, const float* __restrict__ p,
    const float* __restrict__ ng, unsigned char* __restrict__ s_q,
    unsigned char* __restrict__ cand_q, float* __restrict__ rowsum) {
  const int row = blockIdx.x;
  const int t = threadIdx.x;
  const float* src;
  unsigned char* dst;
  if (row < N_ROWS) {
    src = s + (size_t)row * D_DIM;
    dst = s_q + (size_t)row * D_DIM;
  } else if (row < 2 * N_ROWS) {
    src = p + (size_t)(row - N_ROWS) * D_DIM;
    dst = cand_q + (size_t)(row - N_ROWS) * D_DIM;
  } else {
    src = ng + (size_t)(row - 2 * N_ROWS) * D_DIM;
    dst = cand_q + (size_t)(row - N_ROWS) * D_DIM;
  }

  float4 v = reinterpret_cast<const float4*>(src)[t];
  float ss = v.x * v.x + v.y * v.y + v.z * v.z + v.w * v.w;
#pragma unroll
  for (int m = 32; m >= 1; m >>= 1) ss += __shfl_xor(ss, m, 64);
  __shared__ float red[4];
  const int w = t >> 6, l = t & 63;
  if (l == 0) red[w] = ss;
  __syncthreads();
  const float tot = red[0] + red[1] + red[2] + red[3];
  const float scale = 1.0f / fmaxf(sqrtf(tot), 1e-8f);

  int pk = __builtin_amdgcn_cvt_pk_fp8_f32(v.x * scale, v.y * scale, 0, false);
  pk = __builtin_amdgcn_cvt_pk_fp8_f32(v.z * scale, v.w * scale, pk, true);
  *reinterpret_cast<unsigned*>(dst + t * 4) = (unsigned)pk;

  if (t == 0 && row < N_ROWS) rowsum[row] = 0.0f;
}

// ---------------------------------------------------------------------------
// Kernel 2: fused MX-fp8 GEMM + exp-rowsum. 256x256, BK=64, 8 waves (2Mx4N),
// mfma_scale_f32_32x32x64_f8f6f4 with unit scales (127 -> x1.0): 2x the
// non-scaled fp8 rate. Per wave: 4 M-frags x 2 N-frags = 8 MFMA per K-tile.
// 4 LDS buffers, staged 2 tiles ahead, ONE barrier per K-tile; counted
// vmcnt(4) per tile (never 0 until tail). LDS 16B-slot rotation
// phys = (s + ((row>>1)&3)) & 3 keeps all 8 4-bank spans distinct per
// 8-lane quantum -> conflict-free b128 reads.
// ---------------------------------------------------------------------------
__global__ __launch_bounds__(512, 2) void gemm_lse_kernel(
    const unsigned char* __restrict__ s_q,
    const unsigned char* __restrict__ cand_q,
    float* __restrict__ rowsum, float* __restrict__ pos) {
  __shared__ __align__(16) unsigned char lds[131072];  // 4 x (A 16K | B 16K)

  const int t = threadIdx.x;
  const int w = t >> 6;
  const int l = t & 63;
  const int l31 = l & 31;
  const int h = l >> 5;           // k-half of the fragment
  const int wm = w >> 2;
  const int wn = w & 3;
  const int rowBase = blockIdx.y * BM;
  const int colBase = blockIdx.x * BN;

  // lane-constant phys slots for the two 16B reads of each 32B fragment:
  // logical slots ks, ks+1 with ks = h*2; rotation c = ((l&31)>>1)&3.
  const int cc = (l31 >> 1) & 3;
  const int p0 = ((h * 2) + cc) & 3;
  const int p1 = ((h * 2) + 1 + cc) & 3;

  f32x16 acc[8] = {};  // [m2*2+n2]
  i32x8 af[4];
  i32x8 bf[2];

  // staging: thread t writes linear LDS dst t*16 = phys slot (t&3) of local
  // row (t>>2); fetch logical slot = (phys - ((row>>1)&3)) & 3.
  const int sRow = t >> 2;                      // 0..127
  const int sSlotL = ((t & 3) - (t >> 3)) & 3;  // logical slot to fetch
  const size_t gA0 = (size_t)(rowBase + sRow) * D_DIM + sSlotL * 16;
  const size_t gB0 = (size_t)(colBase + sRow) * D_DIM + sSlotL * 16;

  auto stageA = [&](int T, int hh) {
    const unsigned char* src =
        s_q + gA0 + (size_t)hh * (128 * D_DIM) + T * 64;
    unsigned char* dst = lds + (T & 3) * 32768 + hh * 8192 + t * 16;
    __builtin_amdgcn_global_load_lds((const gvoid*)src, (lvoid*)dst, 16, 0, 0);
  };
  auto stageB = [&](int T, int hh) {
    const unsigned char* src =
        cand_q + gB0 + (size_t)hh * (128 * D_DIM) + T * 64;
    unsigned char* dst = lds + (T & 3) * 32768 + 16384 + hh * 8192 + t * 16;
    __builtin_amdgcn_global_load_lds((const gvoid*)src, (lvoid*)dst, 16, 0, 0);
  };

  auto loadA = [&](int T) {
    const unsigned char* A = lds + (T & 3) * 32768;
#pragma unroll
    for (int m2 = 0; m2 < 4; ++m2) {
      const int r = wm * 128 + m2 * 32 + l31;
      i32x4 v0 = *reinterpret_cast<const i32x4*>(A + r * 64 + p0 * 16);
      i32x4 v1 = *reinterpret_cast<const i32x4*>(A + r * 64 + p1 * 16);
      af[m2] = __builtin_shufflevector(v0, v1, 0, 1, 2, 3, 4, 5, 6, 7);
    }
  };
  auto loadB = [&](int T) {
    const unsigned char* B = lds + (T & 3) * 32768 + 16384;
#pragma unroll
    for (int n2 = 0; n2 < 2; ++n2) {
      const int r = wn * 64 + n2 * 32 + l31;
      i32x4 v0 = *reinterpret_cast<const i32x4*>(B + r * 64 + p0 * 16);
      i32x4 v1 = *reinterpret_cast<const i32x4*>(B + r * 64 + p1 * 16);
      bf[n2] = __builtin_shufflevector(v0, v1, 0, 1, 2, 3, 4, 5, 6, 7);
    }
  };

  // --- prologue: stage tiles 0,1; wait tile 0 (tile 1's 4 stay in flight).
  stageA(0, 0); stageA(0, 1); stageB(0, 0); stageB(0, 1);
  stageA(1, 0); stageA(1, 1); stageB(1, 0); stageB(1, 1);
  asm volatile("s_waitcnt vmcnt(4)" ::: "memory");
  SCHED0();
  BAR(); SCHED0();

  for (int T = 0; T < NT; ++T) {
    const bool sN = (T + 2 < NT);

    // 12 ds_read_b128 for tile T | stage tile T+2 | 8 MFMA | vmcnt | BAR
    loadA(T); loadB(T);
    if (sN) {
      stageA(T + 2, 0); stageA(T + 2, 1);
      stageB(T + 2, 0); stageB(T + 2, 1);
    }
    __builtin_amdgcn_s_setprio(1);
#pragma unroll
    for (int m2 = 0; m2 < 4; ++m2)
#pragma unroll
      for (int n2 = 0; n2 < 2; ++n2)
        acc[m2 * 2 + n2] = __builtin_amdgcn_mfma_scale_f32_32x32x64_f8f6f4(
            af[m2], bf[n2], acc[m2 * 2 + n2], 0, 0, 0, 127, 0, 127);
    __builtin_amdgcn_s_setprio(0);

    if (T <= NT - 3) {
      asm volatile("s_waitcnt vmcnt(4)" ::: "memory");  // T+1 landed
    } else if (T == NT - 2) {
      asm volatile("s_waitcnt vmcnt(0)" ::: "memory");  // tail drain
    }
    SCHED0();
    BAR(); SCHED0();
  }

  // --- epilogue: sim = acc*20; cosine<=1 -> fixed-max logsumexp at 20.
  // 32x32 C/D layout: col = l&31, row = (reg&3) + 8*(reg>>2) + 4*(l>>5).
  __syncthreads();
  float* red = reinterpret_cast<float*>(lds);
  if (t < 256) red[t] = 0.0f;
  __syncthreads();

#pragma unroll
  for (int m2 = 0; m2 < 4; ++m2) {
#pragma unroll
    for (int r = 0; r < 16; ++r) {
      const int rloc = wm * 128 + m2 * 32 + (r & 3) + 8 * (r >> 2) + 4 * h;
      const int rowg = rowBase + rloc;
      float sm = 0.0f;
#pragma unroll
      for (int n2 = 0; n2 < 2; ++n2) {
        const int colg = colBase + wn * 64 + n2 * 32 + l31;
        const float simv = acc[m2 * 2 + n2][r] * TEMP_INV;
        if (colg == rowg) pos[rowg] = simv;
        sm += __expf(simv - TEMP_INV);
      }
      sm += __shfl_xor(sm, 1, 64);
      sm += __shfl_xor(sm, 2, 64);
      sm += __shfl_xor(sm, 4, 64);
      sm += __shfl_xor(sm, 8, 64);
      sm += __shfl_xor(sm, 16, 64);
      if (l31 == 0) atomicAdd(&red[rloc], sm);
    }
  }
  __syncthreads();
  if (t < 256) atomicAdd(&rowsum[rowBase + t], red[t]);
}

// ---------------------------------------------------------------------------
// Kernel 3: loss = mean(20 + log(rowsum) - pos)
// ---------------------------------------------------------------------------
__global__ __launch_bounds__(1024) void loss_kernel(
    const float* __restrict__ rowsum, const float* __restrict__ pos,
    float* __restrict__ out) {
  const int t = threadIdx.x;
  float acc = 0.0f;
  for (int i = t; i < N_ROWS; i += 1024)
    acc += TEMP_INV + logf(rowsum[i]) - pos[i];
#pragma unroll
  for (int m = 32; m >= 1; m >>= 1) acc += __shfl_xor(acc, m, 64);
  __shared__ float red[16];
  const int w = t >> 6, l = t & 63;
  if (l == 0) red[w] = acc;
  __syncthreads();
  if (t == 0) {
    float tot = 0.0f;
#pragma unroll
    for (int i = 0; i < 16; ++i) tot += red[i];
    out[0] = tot / (float)N_ROWS;
  }
}

// ---------------------------------------------------------------------------
extern "C" void kernel_launch(void* const* d_in, const int* in_sizes, int n_in,
                              void* d_out, int out_size, void* d_ws,
                              size_t ws_size, hipStream_t stream) {
  (void)in_sizes; (void)n_in; (void)out_size; (void)ws_size;
  const float* s = (const float*)d_in[0];
  const float* p = (const float*)d_in[1];
  const float* ng = (const float*)d_in[2];

  unsigned char* s_q = (unsigned char*)d_ws;                      // 4 MB
  unsigned char* cand_q = s_q + (size_t)N_ROWS * D_DIM;           // 8 MB
  float* rowsum = (float*)(cand_q + (size_t)N_CAND * D_DIM);      // 16 KB
  float* pos = rowsum + N_ROWS;                                   // 16 KB
  float* out = (float*)d_out;

  prep_kernel<<<dim3(3 * N_ROWS), dim3(256), 0, stream>>>(s, p, ng, s_q,
                                                          cand_q, rowsum);
  gemm_lse_kernel<<<dim3(N_CAND / BN, N_ROWS / BM), dim3(512), 0, stream>>>(
      s_q, cand_q, rowsum, pos);
  loss_kernel<<<dim3(1), dim3(1024), 0, stream>>>(rowsum, pos, out);
}